// Round 6
// baseline (6793.102 us; speedup 1.0000x reference)
//
#include <hip/hip_runtime.h>
#include <hip/hip_bf16.h>

#define TT 1024
#define NBLK 256

typedef __attribute__((ext_vector_type(8))) short v8s;
typedef __attribute__((ext_vector_type(4))) float v4f;

__device__ __forceinline__ unsigned short f2b(float f){
  union { float f; unsigned u; } v; v.f = f;
  unsigned r = v.u + 0x7FFFu + ((v.u >> 16) & 1u);
  return (unsigned short)(r >> 16);
}
__device__ __forceinline__ float sigm(float x){ return 1.f/(1.f+__expf(-x)); }
__device__ __forceinline__ float tanh_(float x){
  float xc = fminf(fmaxf(x, -15.f), 15.f);
  float e = __expf(2.f*xc);
  return (e-1.f)/(e+1.f);
}

// Plain cached 16B load. Safe for h data despite cross-XCD production:
// every h address is written exactly once (agent-scope producer store that
// reaches the coherence point before the flag), and is only loaded AFTER the
// flag for that slot is observed -- so no stale L1/L2 line can exist.
__device__ __forceinline__ v8s ldP(const unsigned short* p){
  return *(const v8s*)p;
}

// Per-wave producer-slice poll, 2-deep software-pipelined tight spin:
// two agent-scope loads stay in flight, checks alternate -> detect
// granularity ~ RTT/2 instead of RTT (and no s_sleep quantization).
__device__ __forceinline__ void poll_slice(const unsigned* flags, int fi, unsigned tgt){
  const unsigned* fp = flags + (size_t)fi * 16;
  unsigned va = __hip_atomic_load(fp, __ATOMIC_RELAXED, __HIP_MEMORY_SCOPE_AGENT);
  unsigned vb = __hip_atomic_load(fp, __ATOMIC_RELAXED, __HIP_MEMORY_SCOPE_AGENT);
  while (true){
    if (__all((int)(va >= tgt))) break;
    va = __hip_atomic_load(fp, __ATOMIC_RELAXED, __HIP_MEMORY_SCOPE_AGENT);
    if (__all((int)(vb >= tgt))) break;
    vb = __hip_atomic_load(fp, __ATOMIC_RELAXED, __HIP_MEMORY_SCOPE_AGENT);
  }
}

// One LSTM layer, persistent. Each block owns 8 hidden units (32 z-cols: 4 gates x 8).
// 9 waves: waves 0..7 split K (NK k-steps of 32 each) with weights resident in
// VGPRs; WAVE 8 is a dedicated store/flag tail wave -- after barrier-2 it does
// h-store -> s_waitcnt(0) ack -> flag store while waves 0..7 run ahead into
// step t+1's poll+MFMA. This takes the agent-store ack round trip off the
// per-step critical cycle (previously wave 0 did both, delaying barrier-1 of
// t+1 by the full ack every step).
//
// h layout BLOCK-MAJOR: h[t][blk][m][8units] (512B per block per step, 8
// exclusive contiguous 64B lines). Element (m, dim) at (dim>>3)*256+m*8+(dim&7).
template<int NK, int KX, int XS, bool XBM, bool L2L, int XFLAG, int HFLAG>
__device__ void run_layer(const unsigned short* __restrict__ xseq,
                          unsigned short* __restrict__ hseq,
                          const float* __restrict__ Wx,
                          const float* __restrict__ Wh,
                          const float* __restrict__ bias,
                          unsigned* __restrict__ flags,
                          int myidx, int ub,
                          float (*red)[32][36],
                          unsigned short* hstage)
{
  const int tid  = threadIdx.x;
  const int lane = tid & 63;
  const int wave = tid >> 6;          // 0..8
  const int l15  = lane & 15;
  const int qd   = lane >> 4;
  const int q8   = qd * 8;
  constexpr bool XPOLL = (XFLAG >= 0);   // x stream is flag-protected (layer 2)

  const int ksk = wave * (NK * 32);
  unsigned* myflag = flags + (size_t)((L2L ? 128 : 0) + myidx) * 16;

  // ---- per-wave flag slice: producers covering k-range [ksk, ksk+NK*32) ----
  // (wave 8's range is past K, so nx=nh=0 naturally)
  int nx = 0, fx0 = 0;
  if (XPOLL){
    int xs = ksk < KX ? ksk : KX;
    int xe = (ksk + NK*32) < KX ? (ksk + NK*32) : KX;
    if (xe > xs){ fx0 = XFLAG + (xs >> 3); nx = ((xe - 1) >> 3) - (xs >> 3) + 1; }
  }
  int nh = 0, fh0 = 0;
  {
    int hs = ksk - KX; if (hs < 0) hs = 0;
    int he = ksk + NK*32 - KX; if (he > 1024) he = 1024;
    if (he > hs){ fh0 = HFLAG + (hs >> 3); nh = ((he - 1) >> 3) - (hs >> 3) + 1; }
  }
  const int ntot = nx + nh;
  int myfi = 0;
  if (ntot > 0){
    int i = lane < ntot ? lane : ntot - 1;   // surplus lanes duplicate last flag
    myfi = (i < nx) ? (fx0 + i) : (fh0 + (i - nx));
  }

  // ---- one-time: load weight fragments (fp32 -> bf16) into registers ----
  v8s wf[NK][2];
  if (wave < 8){
    #pragma unroll
    for (int ks = 0; ks < NK; ++ks){
      #pragma unroll
      for (int nt = 0; nt < 2; ++nt){
        int c = nt*16 + l15;                       // local col 0..31
        int gcol = (c >> 3) * 1024 + ub + (c & 7); // gate*1024 + unit
        int kb = ksk + ks*32 + q8;
        #pragma unroll
        for (int j = 0; j < 8; ++j){
          int k = kb + j;
          float v = (k < KX) ? Wx[(size_t)k * 4096 + gcol]
                             : Wh[(size_t)(k - KX) * 4096 + gcol];
          wf[ks][nt][j] = (short)f2b(v);
        }
      }
    }
  }

  // per-thread gate state: threads 0..255 handle (m = tid>>3, u = tid&7)
  float cst = 0.f;
  float bz[4] = {0.f,0.f,0.f,0.f};
  if (tid < 256){
    int u = tid & 7;
    #pragma unroll
    for (int g = 0; g < 4; ++g) bz[g] = bias[g*1024 + ub + u];
  }

  for (int w = 0; w <= TT; ++w){
    const bool active = L2L ? (w >= 1) : (w < TT);
    const int t = L2L ? (w - 1) : w;
    if (active && wave < 8){
      if (ntot > 0) poll_slice(flags, myfi, (unsigned)w);
      // forbid hoisting the (plain, cached) data loads above the poll
      asm volatile("" ::: "memory");

      const unsigned short* xb = xseq + (size_t)(t + (L2L ? 1 : 0)) * (size_t)(XS * 32);
      const unsigned short* hb = hseq + (size_t)t * 32768;
      v4f acc[2][2];
      #pragma unroll
      for (int mt = 0; mt < 2; ++mt)
        #pragma unroll
        for (int nt = 0; nt < 2; ++nt)
          acc[mt][nt] = (v4f){0.f,0.f,0.f,0.f};

      #pragma unroll
      for (int ks = 0; ks < NK; ++ks){
        int k = ksk + ks*32;
        v8s a0, a1;
        if (k < KX){
          if (XBM){
            // block-major x (h1 feeding layer 2)
            const unsigned short* p = xb + (size_t)((k + q8) >> 3) * 256 + (size_t)l15 * 8;
            a0 = ldP(p);
            a1 = ldP(p + 128);          // m += 16
          } else {
            // row-major x (obs feeding layer 1)
            const unsigned short* p = xb + k + (size_t)l15 * XS + q8;
            a0 = ldP(p);
            a1 = ldP(p + (size_t)16 * XS);
          }
        } else {
          // block-major h
          const unsigned short* p = hb + (size_t)((k - KX + q8) >> 3) * 256 + (size_t)l15 * 8;
          a0 = ldP(p);
          a1 = ldP(p + 128);            // m += 16
        }
        acc[0][0] = __builtin_amdgcn_mfma_f32_16x16x32_bf16(a0, wf[ks][0], acc[0][0], 0,0,0);
        acc[0][1] = __builtin_amdgcn_mfma_f32_16x16x32_bf16(a0, wf[ks][1], acc[0][1], 0,0,0);
        acc[1][0] = __builtin_amdgcn_mfma_f32_16x16x32_bf16(a1, wf[ks][0], acc[1][0], 0,0,0);
        acc[1][1] = __builtin_amdgcn_mfma_f32_16x16x32_bf16(a1, wf[ks][1], acc[1][1], 0,0,0);
      }
      // C/D layout: col = lane&15, row = (lane>>4)*4 + r
      #pragma unroll
      for (int mt = 0; mt < 2; ++mt)
        #pragma unroll
        for (int nt = 0; nt < 2; ++nt)
          #pragma unroll
          for (int r = 0; r < 4; ++r)
            red[wave][mt*16 + qd*4 + r][nt*16 + l15] = acc[mt][nt][r];
    }
    __syncthreads();
    if (active && tid < 256){
      int m = tid >> 3, u = tid & 7;
      float z[4];
      #pragma unroll
      for (int g = 0; g < 4; ++g){
        float s = bz[g];
        #pragma unroll
        for (int w8 = 0; w8 < 8; ++w8) s += red[w8][m][g*8 + u];
        z[g] = s;
      }
      float i  = sigm(z[0]);
      float f  = sigm(z[1]);
      float gg = tanh_(z[2]);
      float o  = sigm(z[3]);
      cst = f*cst + i*gg;
      float hv = o * tanh_(cst);
      hstage[m*8 + u] = f2b(hv);
    }
    __syncthreads();
    if (tid >= 512){                  // dedicated tail wave (wave 8)
      int st = tid - 512;             // 0..63
      if (active){
        // hstage is [m][8u] contiguous == exactly the block-major layout:
        // one contiguous 512B region (8 exclusive 64B lines), 64 x 8B coalesced.
        unsigned long long v = ((const unsigned long long*)hstage)[st];
        unsigned long long* dst = (unsigned long long*)
            (hseq + (size_t)(t+1)*32768 + (size_t)myidx*256) + st;
        __hip_atomic_store(dst, v, __ATOMIC_RELAXED, __HIP_MEMORY_SCOPE_AGENT);
      }
      __builtin_amdgcn_s_waitcnt(0);   // h stores globally visible before flag
      if (tid == 512)
        __hip_atomic_store(myflag, (unsigned)(w+1), __ATOMIC_RELAXED, __HIP_MEMORY_SCOPE_AGENT);
    }
  }
}

__global__ __launch_bounds__(576, 1)
void lstm_persist(const unsigned short* __restrict__ obsb,
                  unsigned short* __restrict__ h1,
                  unsigned short* __restrict__ h2,
                  const float* __restrict__ W1x, const float* __restrict__ W1h,
                  const float* __restrict__ b1,
                  const float* __restrict__ W2x, const float* __restrict__ W2h,
                  const float* __restrict__ b2,
                  unsigned* __restrict__ flags)
{
  __shared__ float red[8][32][36];
  __shared__ unsigned short hstage[256];
  int blk = blockIdx.x;
  if (blk < 128){
    // layer 1: K = 256 (obs row-major, no poll) + 1024 (h1 block-major, flags group 0)
    run_layer<5, 256, 256, false, false, -1, 0>(obsb, h1, W1x, W1h, b1, flags, blk, blk*8, red, hstage);
  } else {
    // layer 2: K = 1024 (h1 block-major, flags group 0) + 1024 (h2 block-major, flags group 128)
    run_layer<8, 1024, 1024, true, true, 0, 128>(h1, h2, W2x, W2h, b2, flags, blk-128, (blk-128)*8, red, hstage);
  }
}

// obs [32,1024,256] fp32 -> obsb [t][m][k] bf16  (row-major, unchanged)
__global__ void obs_conv(const float* __restrict__ obs, unsigned short* __restrict__ obsb){
  int idx = blockIdx.x * 256 + threadIdx.x;      // 2,097,152 total
  int k4 = idx & 63;
  int rest = idx >> 6;
  int m = rest & 31;
  int t = rest >> 5;
  const float4 v = *(const float4*)(obs + (size_t)m*262144 + (size_t)t*256 + k4*4);
  ushort4 o;
  o.x = f2b(v.x); o.y = f2b(v.y); o.z = f2b(v.z); o.w = f2b(v.w);
  *(ushort4*)(obsb + (size_t)t*8192 + m*256 + k4*4) = o;
}

// pack [Wm | Wc] -> BT[n][k] bf16 (transposed, n-major)
__global__ void head_pack(const float* __restrict__ Wm, const float* __restrict__ Wc,
                          unsigned short* __restrict__ wt){
  int idx = blockIdx.x * 256 + threadIdx.x;      // 1,048,576 total
  int k = idx & 1023;
  int n = idx >> 10;
  float v = (n < 512) ? Wm[(size_t)k*512 + n] : Wc[(size_t)k*512 + (n-512)];
  wt[(size_t)n*1024 + k] = f2b(v);
}

// heads: [32768,1024] x [1024,1024], epilogue adds bias, softplus on cov half.
// A (= h2 slots 1..1024) is BLOCK-MAJOR: element (M, k) with t=M>>5, m=M&31 at
// t*32768 + (k>>3)*256 + m*8 + (k&7).
__global__ __launch_bounds__(256, 2)
void heads_gemm(const unsigned short* __restrict__ A,
                const unsigned short* __restrict__ BT,
                const float* __restrict__ bm, const float* __restrict__ bc,
                float* __restrict__ out)
{
  __shared__ short LA[128][40];
  __shared__ short LB[128][40];
  const int tid  = threadIdx.x;
  const int lane = tid & 63;
  const int wave = tid >> 6;
  const int wm = wave & 1, wn = wave >> 1;
  const int l15 = lane & 15, qd = lane >> 4;
  const int bm0 = blockIdx.x * 128;
  const int bn0 = blockIdx.y * 128;

  v4f acc[4][4];
  #pragma unroll
  for (int i = 0; i < 4; ++i)
    #pragma unroll
    for (int j = 0; j < 4; ++j)
      acc[i][j] = (v4f){0.f,0.f,0.f,0.f};

  for (int k0 = 0; k0 < 1024; k0 += 32){
    __syncthreads();
    #pragma unroll
    for (int i = 0; i < 2; ++i){
      int c = tid + i*256;                 // 512 16B chunks each for A and B
      int row = c >> 2, kc = (c & 3) * 8;
      int M = bm0 + row;
      int tt = M >> 5, mm = M & 31;
      *(v8s*)&LA[row][kc] = *(const v8s*)&A [(size_t)tt*32768 + (size_t)((k0 + kc) >> 3)*256 + mm*8];
      *(v8s*)&LB[row][kc] = *(const v8s*)&BT[(size_t)(bn0 + row)*1024 + k0 + kc];
    }
    __syncthreads();
    v8s a[4], b[4];
    #pragma unroll
    for (int mt = 0; mt < 4; ++mt) a[mt] = *(const v8s*)&LA[wm*64 + mt*16 + l15][qd*8];
    #pragma unroll
    for (int nt = 0; nt < 4; ++nt) b[nt] = *(const v8s*)&LB[wn*64 + nt*16 + l15][qd*8];
    #pragma unroll
    for (int mt = 0; mt < 4; ++mt)
      #pragma unroll
      for (int nt = 0; nt < 4; ++nt)
        acc[mt][nt] = __builtin_amdgcn_mfma_f32_16x16x32_bf16(a[mt], b[nt], acc[mt][nt], 0,0,0);
  }

  #pragma unroll
  for (int mt = 0; mt < 4; ++mt){
    #pragma unroll
    for (int nt = 0; nt < 4; ++nt){
      #pragma unroll
      for (int r = 0; r < 4; ++r){
        int rg = bm0 + wm*64 + mt*16 + qd*4 + r;
        int cg = bn0 + wn*64 + nt*16 + l15;
        int t = rg >> 5, b_ = rg & 31;
        float v = acc[mt][nt][r];
        if (cg < 512){
          out[((size_t)b_*1024 + t)*512 + cg] = v + bm[cg];
        } else {
          float x = v + bc[cg - 512];
          float sp = fmaxf(x, 0.f) + log1pf(__expf(-fabsf(x)));
          out[(size_t)16777216 + ((size_t)b_*1024 + t)*512 + (cg - 512)] = sp;
        }
      }
    }
  }
}

extern "C" void kernel_launch(void* const* d_in, const int* in_sizes, int n_in,
                              void* d_out, int out_size, void* d_ws, size_t ws_size,
                              hipStream_t stream)
{
  const float* obs = (const float*)d_in[0];
  const float* W1x = (const float*)d_in[1];
  const float* W1h = (const float*)d_in[2];
  const float* b1  = (const float*)d_in[3];
  const float* W2x = (const float*)d_in[4];
  const float* W2h = (const float*)d_in[5];
  const float* b2  = (const float*)d_in[6];
  const float* Wm  = (const float*)d_in[7];
  const float* bm  = (const float*)d_in[8];
  const float* Wc  = (const float*)d_in[9];
  const float* bc  = (const float*)d_in[10];
  float* out = (float*)d_out;

  char* wsb = (char*)d_ws;
  unsigned* flags      = (unsigned*)wsb;                      // 256 flags x 64B = 16KB
  unsigned short* h1   = (unsigned short*)(wsb + 16384);      // [1025][128blk][32][8] bf16
  unsigned short* h2   = h1 + (size_t)1025*32768;             // [1025][128blk][32][8] bf16
  unsigned short* obsb = h2 + (size_t)1025*32768;             // [1024][32][256]  bf16
  unsigned short* wht  = obsb + (size_t)1024*8192;            // [1024][1024]     bf16

  hipMemsetAsync(flags, 0, 16384, stream);
  hipMemsetAsync(h1, 0, 65536, stream);   // h1 slot 0 = h_{-1} = 0
  hipMemsetAsync(h2, 0, 65536, stream);   // h2 slot 0 = 0

  obs_conv <<<8192, 256, 0, stream>>>(obs, obsb);
  head_pack<<<4096, 256, 0, stream>>>(Wm, Wc, wht);

  const unsigned short* obsb_c = obsb;
  void* kargs[] = { (void*)&obsb_c, (void*)&h1, (void*)&h2,
                    (void*)&W1x, (void*)&W1h, (void*)&b1,
                    (void*)&W2x, (void*)&W2h, (void*)&b2, (void*)&flags };
  hipLaunchCooperativeKernel((void*)lstm_persist, dim3(NBLK), dim3(576), kargs, 0, stream);

  const unsigned short* Ah = h2 + 32768;   // h2 slots 1..1024 -> [32768 M][1024 k] block-major
  heads_gemm<<<dim3(256, 8), 256, 0, stream>>>(Ah, wht, bm, bc, out);
}

// Round 7
// 4486.486 us; speedup vs baseline: 1.5141x; 1.5141x over previous
//
#include <hip/hip_runtime.h>
#include <hip/hip_bf16.h>

#define TT 1024
#define NBLK 256
#define SENT 0xFFFFFFFFFFFFFFFFULL

typedef __attribute__((ext_vector_type(8))) short v8s;
typedef __attribute__((ext_vector_type(4))) float v4f;

__device__ __forceinline__ unsigned short f2b(float f){
  union { float f; unsigned u; } v; v.f = f;
  unsigned r = v.u + 0x7FFFu + ((v.u >> 16) & 1u);
  return (unsigned short)(r >> 16);
}
__device__ __forceinline__ float sigm(float x){ return 1.f/(1.f+__expf(-x)); }
__device__ __forceinline__ float tanh_(float x){
  float xc = fminf(fmaxf(x, -15.f), 15.f);
  float e = __expf(2.f*xc);
  return (e-1.f)/(e+1.f);
}

// Plain cached 16B load (obs stream only -- ready before launch).
__device__ __forceinline__ v8s ldP(const unsigned short* p){
  return *(const v8s*)p;
}
__device__ __forceinline__ unsigned long long ldAq(const unsigned long long* q){
  return __hip_atomic_load(q, __ATOMIC_RELAXED, __HIP_MEMORY_SCOPE_AGENT);
}

// One LSTM layer, persistent. Each block owns 8 hidden units (32 z-cols: 4 gates x 8).
// K (= KX input dims + 1024 recurrent dims) split across 8 waves, NK k-steps of 32 each.
// Weights resident in VGPRs as MFMA B-fragments for the whole sequence.
//
// SENTINEL PROTOCOL (no flags): h buffers are pre-filled with 0xFF bytes
// (bf16 -NaN). Producers just issue agent-scope 8B stores of h (|h|<=1, so a
// written word can never be all-ones). Consumers load their fragments with
// agent-scope 8B atomic loads and re-load any word still == sentinel; the
// arrival of data IS the readiness signal. This collapses the old
// store-drain RTT + flag-visibility RTT + data-load RTT into ONE RTT.
//
// h layout BLOCK-MAJOR: h[t][blk][m][8units] (512B per block per step, 8
// exclusive contiguous 64B lines). Element (m, dim) at (dim>>3)*256+m*8+(dim&7).
template<int NK, int KX, int XS, bool XBM, bool L2L>
__device__ void run_layer(const unsigned short* __restrict__ xseq,
                          unsigned short* __restrict__ hseq,
                          const float* __restrict__ Wx,
                          const float* __restrict__ Wh,
                          const float* __restrict__ bias,
                          int myidx, int ub,
                          float (*red)[32][36],
                          unsigned short* hstage)
{
  const int tid  = threadIdx.x;
  const int lane = tid & 63;
  const int wave = tid >> 6;          // 0..7
  const int l15  = lane & 15;
  const int qd   = lane >> 4;
  const int q8   = qd * 8;

  const int ksk = wave * (NK * 32);

  // ---- one-time: load weight fragments (fp32 -> bf16) into registers ----
  v8s wf[NK][2];
  #pragma unroll
  for (int ks = 0; ks < NK; ++ks){
    #pragma unroll
    for (int nt = 0; nt < 2; ++nt){
      int c = nt*16 + l15;                       // local col 0..31
      int gcol = (c >> 3) * 1024 + ub + (c & 7); // gate*1024 + unit
      int kb = ksk + ks*32 + q8;
      #pragma unroll
      for (int j = 0; j < 8; ++j){
        int k = kb + j;
        float v = (k < KX) ? Wx[(size_t)k * 4096 + gcol]
                           : Wh[(size_t)(k - KX) * 4096 + gcol];
        wf[ks][nt][j] = (short)f2b(v);
      }
    }
  }

  // per-thread gate state: threads 0..255 handle (m = tid>>3, u = tid&7)
  float cst = 0.f;
  float bz[4] = {0.f,0.f,0.f,0.f};
  if (tid < 256){
    int u = tid & 7;
    #pragma unroll
    for (int g = 0; g < 4; ++g) bz[g] = bias[g*1024 + ub + u];
  }

  union FR { v8s v; unsigned long long q[2]; };

  for (int w = 0; w <= TT; ++w){
    const bool active = L2L ? (w >= 1) : (w < TT);
    const int t = L2L ? (w - 1) : w;
    if (active){
      const unsigned short* xb = xseq + (size_t)(t + (L2L ? 1 : 0)) * (size_t)(XS * 32);
      const unsigned short* hb = hseq + (size_t)t * 32768;

      // ---- issue all fragment loads (agent-scope for produced streams) ----
      FR a0[NK], a1[NK];
      #pragma unroll
      for (int ks = 0; ks < NK; ++ks){
        int k = ksk + ks*32;
        if (k < KX && !XBM){
          // row-major obs (no sync needed)
          const unsigned short* p = xb + k + (size_t)l15 * XS + q8;
          a0[ks].v = ldP(p);
          a1[ks].v = ldP(p + (size_t)16 * XS);
        } else {
          const unsigned short* p = (k < KX)
            ? xb + (size_t)((k + q8) >> 3) * 256 + (size_t)l15 * 8
            : hb + (size_t)((k - KX + q8) >> 3) * 256 + (size_t)l15 * 8;
          const unsigned long long* q = (const unsigned long long*)p;
          a0[ks].q[0] = ldAq(q);
          a0[ks].q[1] = ldAq(q + 1);
          const unsigned long long* q2 = (const unsigned long long*)(p + 128); // m += 16
          a1[ks].q[0] = ldAq(q2);
          a1[ks].q[1] = ldAq(q2 + 1);
        }
      }
      // ---- retry any word still sentinel (data not yet arrived) ----
      while (true){
        bool bad = false;
        #pragma unroll
        for (int ks = 0; ks < NK; ++ks){
          int k = ksk + ks*32;
          if (k < KX && !XBM) continue;    // obs: never sentinel-checked
          const unsigned short* p = (k < KX)
            ? xb + (size_t)((k + q8) >> 3) * 256 + (size_t)l15 * 8
            : hb + (size_t)((k - KX + q8) >> 3) * 256 + (size_t)l15 * 8;
          const unsigned long long* q  = (const unsigned long long*)p;
          const unsigned long long* q2 = (const unsigned long long*)(p + 128);
          if (a0[ks].q[0] == SENT){ a0[ks].q[0] = ldAq(q);      bad = true; }
          if (a0[ks].q[1] == SENT){ a0[ks].q[1] = ldAq(q + 1);  bad = true; }
          if (a1[ks].q[0] == SENT){ a1[ks].q[0] = ldAq(q2);     bad = true; }
          if (a1[ks].q[1] == SENT){ a1[ks].q[1] = ldAq(q2 + 1); bad = true; }
        }
        if (!__any((int)bad)) break;
      }

      // ---- MFMA ----
      v4f acc[2][2];
      #pragma unroll
      for (int mt = 0; mt < 2; ++mt)
        #pragma unroll
        for (int nt = 0; nt < 2; ++nt)
          acc[mt][nt] = (v4f){0.f,0.f,0.f,0.f};
      #pragma unroll
      for (int ks = 0; ks < NK; ++ks){
        acc[0][0] = __builtin_amdgcn_mfma_f32_16x16x32_bf16(a0[ks].v, wf[ks][0], acc[0][0], 0,0,0);
        acc[0][1] = __builtin_amdgcn_mfma_f32_16x16x32_bf16(a0[ks].v, wf[ks][1], acc[0][1], 0,0,0);
        acc[1][0] = __builtin_amdgcn_mfma_f32_16x16x32_bf16(a1[ks].v, wf[ks][0], acc[1][0], 0,0,0);
        acc[1][1] = __builtin_amdgcn_mfma_f32_16x16x32_bf16(a1[ks].v, wf[ks][1], acc[1][1], 0,0,0);
      }
      // C/D layout: col = lane&15, row = (lane>>4)*4 + r
      #pragma unroll
      for (int mt = 0; mt < 2; ++mt)
        #pragma unroll
        for (int nt = 0; nt < 2; ++nt)
          #pragma unroll
          for (int r = 0; r < 4; ++r)
            red[wave][mt*16 + qd*4 + r][nt*16 + l15] = acc[mt][nt][r];
    }
    __syncthreads();
    if (active && tid < 256){
      int m = tid >> 3, u = tid & 7;
      float z[4];
      #pragma unroll
      for (int g = 0; g < 4; ++g){
        float s = bz[g];
        #pragma unroll
        for (int w8 = 0; w8 < 8; ++w8) s += red[w8][m][g*8 + u];
        z[g] = s;
      }
      float i  = sigm(z[0]);
      float f  = sigm(z[1]);
      float gg = tanh_(z[2]);
      float o  = sigm(z[3]);
      cst = f*cst + i*gg;
      float hv = o * tanh_(cst);
      hstage[m*8 + u] = f2b(hv);
    }
    __syncthreads();
    if (active && tid < 64){
      // hstage is [m][8u] contiguous == exactly the block-major layout:
      // one contiguous 512B region (8 exclusive 64B lines), 64 x 8B coalesced.
      // Fire-and-forget agent stores: no drain, no flag -- data IS the signal.
      unsigned long long v = ((const unsigned long long*)hstage)[tid];
      unsigned long long* dst = (unsigned long long*)
          (hseq + (size_t)(t+1)*32768 + (size_t)myidx*256) + tid;
      __hip_atomic_store(dst, v, __ATOMIC_RELAXED, __HIP_MEMORY_SCOPE_AGENT);
    }
  }
}

__global__ __launch_bounds__(512, 1)
void lstm_persist(const unsigned short* __restrict__ obsb,
                  unsigned short* __restrict__ h1,
                  unsigned short* __restrict__ h2,
                  const float* __restrict__ W1x, const float* __restrict__ W1h,
                  const float* __restrict__ b1,
                  const float* __restrict__ W2x, const float* __restrict__ W2h,
                  const float* __restrict__ b2)
{
  __shared__ float red[8][32][36];
  __shared__ unsigned short hstage[256];
  int blk = blockIdx.x;
  if (blk < 128){
    // layer 1: K = 256 (obs row-major) + 1024 (h1 block-major, sentinel-polled)
    run_layer<5, 256, 256, false, false>(obsb, h1, W1x, W1h, b1, blk, blk*8, red, hstage);
  } else {
    // layer 2: K = 1024 (h1 block-major) + 1024 (h2 block-major), all sentinel-polled
    run_layer<8, 1024, 1024, true, true>(h1, h2, W2x, W2h, b2, blk-128, (blk-128)*8, red, hstage);
  }
}

// obs [32,1024,256] fp32 -> obsb [t][m][k] bf16  (row-major)
__global__ void obs_conv(const float* __restrict__ obs, unsigned short* __restrict__ obsb){
  int idx = blockIdx.x * 256 + threadIdx.x;      // 2,097,152 total
  int k4 = idx & 63;
  int rest = idx >> 6;
  int m = rest & 31;
  int t = rest >> 5;
  const float4 v = *(const float4*)(obs + (size_t)m*262144 + (size_t)t*256 + k4*4);
  ushort4 o;
  o.x = f2b(v.x); o.y = f2b(v.y); o.z = f2b(v.z); o.w = f2b(v.w);
  *(ushort4*)(obsb + (size_t)t*8192 + m*256 + k4*4) = o;
}

// pack [Wm | Wc] -> BT[n][k] bf16 (transposed, n-major)
__global__ void head_pack(const float* __restrict__ Wm, const float* __restrict__ Wc,
                          unsigned short* __restrict__ wt){
  int idx = blockIdx.x * 256 + threadIdx.x;      // 1,048,576 total
  int k = idx & 1023;
  int n = idx >> 10;
  float v = (n < 512) ? Wm[(size_t)k*512 + n] : Wc[(size_t)k*512 + (n-512)];
  wt[(size_t)n*1024 + k] = f2b(v);
}

// heads: [32768,1024] x [1024,1024], epilogue adds bias, softplus on cov half.
// A (= h2 slots 1..1024) is BLOCK-MAJOR: element (M, k) with t=M>>5, m=M&31 at
// t*32768 + (k>>3)*256 + m*8 + (k&7).
__global__ __launch_bounds__(256, 2)
void heads_gemm(const unsigned short* __restrict__ A,
                const unsigned short* __restrict__ BT,
                const float* __restrict__ bm, const float* __restrict__ bc,
                float* __restrict__ out)
{
  __shared__ short LA[128][40];
  __shared__ short LB[128][40];
  const int tid  = threadIdx.x;
  const int lane = tid & 63;
  const int wave = tid >> 6;
  const int wm = wave & 1, wn = wave >> 1;
  const int l15 = lane & 15, qd = lane >> 4;
  const int bm0 = blockIdx.x * 128;
  const int bn0 = blockIdx.y * 128;

  v4f acc[4][4];
  #pragma unroll
  for (int i = 0; i < 4; ++i)
    #pragma unroll
    for (int j = 0; j < 4; ++j)
      acc[i][j] = (v4f){0.f,0.f,0.f,0.f};

  for (int k0 = 0; k0 < 1024; k0 += 32){
    __syncthreads();
    #pragma unroll
    for (int i = 0; i < 2; ++i){
      int c = tid + i*256;                 // 512 16B chunks each for A and B
      int row = c >> 2, kc = (c & 3) * 8;
      int M = bm0 + row;
      int tt = M >> 5, mm = M & 31;
      *(v8s*)&LA[row][kc] = *(const v8s*)&A [(size_t)tt*32768 + (size_t)((k0 + kc) >> 3)*256 + mm*8];
      *(v8s*)&LB[row][kc] = *(const v8s*)&BT[(size_t)(bn0 + row)*1024 + k0 + kc];
    }
    __syncthreads();
    v8s a[4], b[4];
    #pragma unroll
    for (int mt = 0; mt < 4; ++mt) a[mt] = *(const v8s*)&LA[wm*64 + mt*16 + l15][qd*8];
    #pragma unroll
    for (int nt = 0; nt < 4; ++nt) b[nt] = *(const v8s*)&LB[wn*64 + nt*16 + l15][qd*8];
    #pragma unroll
    for (int mt = 0; mt < 4; ++mt)
      #pragma unroll
      for (int nt = 0; nt < 4; ++nt)
        acc[mt][nt] = __builtin_amdgcn_mfma_f32_16x16x32_bf16(a[mt], b[nt], acc[mt][nt], 0,0,0);
  }

  #pragma unroll
  for (int mt = 0; mt < 4; ++mt){
    #pragma unroll
    for (int nt = 0; nt < 4; ++nt){
      #pragma unroll
      for (int r = 0; r < 4; ++r){
        int rg = bm0 + wm*64 + mt*16 + qd*4 + r;
        int cg = bn0 + wn*64 + nt*16 + l15;
        int t = rg >> 5, b_ = rg & 31;
        float v = acc[mt][nt][r];
        if (cg < 512){
          out[((size_t)b_*1024 + t)*512 + cg] = v + bm[cg];
        } else {
          float x = v + bc[cg - 512];
          float sp = fmaxf(x, 0.f) + log1pf(__expf(-fabsf(x)));
          out[(size_t)16777216 + ((size_t)b_*1024 + t)*512 + (cg - 512)] = sp;
        }
      }
    }
  }
}

extern "C" void kernel_launch(void* const* d_in, const int* in_sizes, int n_in,
                              void* d_out, int out_size, void* d_ws, size_t ws_size,
                              hipStream_t stream)
{
  const float* obs = (const float*)d_in[0];
  const float* W1x = (const float*)d_in[1];
  const float* W1h = (const float*)d_in[2];
  const float* b1  = (const float*)d_in[3];
  const float* W2x = (const float*)d_in[4];
  const float* W2h = (const float*)d_in[5];
  const float* b2  = (const float*)d_in[6];
  const float* Wm  = (const float*)d_in[7];
  const float* bm  = (const float*)d_in[8];
  const float* Wc  = (const float*)d_in[9];
  const float* bc  = (const float*)d_in[10];
  float* out = (float*)d_out;

  char* wsb = (char*)d_ws;
  unsigned short* h1   = (unsigned short*)(wsb + 16384);      // [1025][128blk][32][8] bf16
  unsigned short* h2   = h1 + (size_t)1025*32768;             // [1025][128blk][32][8] bf16
  unsigned short* obsb = h2 + (size_t)1025*32768;             // [1024][32][256]  bf16
  unsigned short* wht  = obsb + (size_t)1024*8192;            // [1024][1024]     bf16

  // slot 0 = h_{-1} = 0; slots 1..1024 = 0xFF sentinel (MUST be re-armed every
  // launch: stale data from a previous run would otherwise pass the check).
  hipMemsetAsync(h1, 0, 65536, stream);
  hipMemsetAsync(h2, 0, 65536, stream);
  hipMemsetAsync(h1 + 32768, 0xFF, (size_t)1024*32768*2, stream);
  hipMemsetAsync(h2 + 32768, 0xFF, (size_t)1024*32768*2, stream);

  obs_conv <<<8192, 256, 0, stream>>>(obs, obsb);
  head_pack<<<4096, 256, 0, stream>>>(Wm, Wc, wht);

  const unsigned short* obsb_c = obsb;
  void* kargs[] = { (void*)&obsb_c, (void*)&h1, (void*)&h2,
                    (void*)&W1x, (void*)&W1h, (void*)&b1,
                    (void*)&W2x, (void*)&W2h, (void*)&b2 };
  hipLaunchCooperativeKernel((void*)lstm_persist, dim3(NBLK), dim3(512), kargs, 0, stream);

  const unsigned short* Ah = h2 + 32768;   // h2 slots 1..1024 -> [32768 M][1024 k] block-major
  heads_gemm<<<dim3(256, 8), 256, 0, stream>>>(Ah, wht, bm, bc, out);
}